// Round 7
// baseline (394.374 us; speedup 1.0000x reference)
//
#include <hip/hip_runtime.h>
#include <hip/hip_bf16.h>

#define N_NODES 50000
#define N_EDGES 800000
#define IN_DIM 64
#define HID_DIM 128
#define OUT_DIM 64
#define NGRP 8
#define NSLC 4                                // feature slices (16 floats each)
#define NE8 (NGRP * N_NODES)                  // 400000 group-major degree entries
#define NBLK8 ((NE8 + 255) / 256)             // 1563 scan blocks (group-major)
#define NBLKN ((N_NODES + 255) / 256)         // 196 scan blocks (merged)

// ---- device-global scratch (no ws_size dependence) ----
__device__ int g_in_f32;
__device__ int g_is64;
__device__ int g_src[N_EDGES];
__device__ int g_dst[N_EDGES];
__device__ int g_csr[N_EDGES];                // group-major partitioned CSR
__device__ int g_mcsr[N_EDGES];               // merged node-major CSR
__device__ int g_deg8[NE8];                   // [g][v] group-major
__device__ int g_rowptr8[NE8 + 1];
__device__ int g_cursor8[NE8];
__device__ int g_mdeg[N_NODES];
__device__ int g_mrp[N_NODES + 1];
__device__ int g_bsum[NBLK8];
__device__ int g_boff[NBLK8];
__device__ int g_bsum2[NBLKN];
__device__ int g_boff2[NBLKN];
__device__ float g_dinv[N_NODES];
__device__ __align__(16) float g_W1f[IN_DIM * HID_DIM];
__device__ __align__(16) float g_W2f[HID_DIM * OUT_DIM];
__device__ __align__(16) float g_b1f[HID_DIM];
__device__ __align__(16) float g_b2f[OUT_DIM];
// g_hs1: aggz out blocked [4][N][16] (N*64), later hs2 blocked [4][N][16]
__device__ __align__(16) float g_hs1[(size_t)N_NODES * HID_DIM];
// g_agg1: zb blocked [4][N][16] (N*64) during aggz, later h row-major (N*128)
__device__ __align__(16) float g_agg1[(size_t)N_NODES * HID_DIM];

__device__ __forceinline__ float loadx(const void* p, int i, int f32) {
    if (f32) return ((const float*)p)[i];
    unsigned int u = ((unsigned int)((const unsigned short*)p)[i]) << 16;
    return __uint_as_float(u);
}

// ---- dtype / index-width detection (data-driven, deterministic) ----
__global__ void detect_kernel(const unsigned short* __restrict__ zw,
                              const unsigned int* __restrict__ ew, int E) {
    __shared__ int s_f32, s_nz;
    if (threadIdx.x == 0) { s_f32 = 0; s_nz = 0; }
    __syncthreads();
    int hit = 0;
    for (int k = 0; k < 64; k++) {
        int i = 2 * ((threadIdx.x * 64 + k) * 97);
        if (((zw[i] >> 7) & 0xFF) == 0xFF) hit = 1;
    }
    if (hit) atomicOr(&s_f32, 1);
    int nz = 0;
    int step = E / 4096;
    for (int k = 0; k < 4; k++) {
        int idx = 1 + 2 * ((threadIdx.x * 4 + k) * step);
        if (ew[idx] != 0) nz = 1;
    }
    if (nz) atomicOr(&s_nz, 1);
    __syncthreads();
    if (threadIdx.x == 0) { g_in_f32 = s_f32; g_is64 = (s_nz == 0) ? 1 : 0; }
}

// ---- zero deg8 + convert weights/biases to f32 scratch (after detect) ----
__global__ void prep_kernel(const void* __restrict__ W1, const void* __restrict__ b1,
                            const void* __restrict__ W2, const void* __restrict__ b2) {
    int i = blockIdx.x * blockDim.x + threadIdx.x;
    if (i < NE8) g_deg8[i] = 0;
    int f32 = g_in_f32;
    if (i < IN_DIM * HID_DIM) g_W1f[i] = loadx(W1, i, f32);
    if (i < HID_DIM * OUT_DIM) g_W2f[i] = loadx(W2, i, f32);
    if (i < HID_DIM) g_b1f[i] = loadx(b1, i, f32);
    if (i < OUT_DIM) g_b2f[i] = loadx(b2, i, f32);
}

// ---- normalize edge_index to int32 + fused per-group degree count ----
__global__ void convert_kernel(const void* __restrict__ ei, int N, int E) {
    int e = blockIdx.x * blockDim.x + threadIdx.x;
    if (e < E) {
        int s, d;
        if (g_is64) {
            const long long* p = (const long long*)ei;
            s = (int)p[e];
            d = (int)p[E + e];
        } else {
            const int* p = (const int*)ei;
            s = p[e];
            d = p[E + e];
        }
        g_src[e] = s;
        g_dst[e] = d;
        int g = blockIdx.x & (NGRP - 1);
        atomicAdd(&g_deg8[g * N + d], 1);
    }
}

// ---- dinv + merged degree from summed per-group degrees ----
__global__ void dinv_kernel(int N) {
    int v = blockIdx.x * blockDim.x + threadIdx.x;
    if (v < N) {
        int s = 0;
#pragma unroll
        for (int g = 0; g < NGRP; g++) s += g_deg8[g * N + v];
        g_mdeg[v] = s;
        g_dinv[v] = rsqrtf((float)s + 1.0f);  // +1 = self loop
    }
}

// ---- phase A: per-block exclusive scan of deg8 (group-major) ----
__global__ __launch_bounds__(256) void localscan_kernel(int NE) {
    __shared__ int sc[256];
    int t = threadIdx.x;
    int idx = blockIdx.x * 256 + t;
    int d = (idx < NE) ? g_deg8[idx] : 0;
    sc[t] = d;
    __syncthreads();
    for (int off = 1; off < 256; off <<= 1) {
        int v = (t >= off) ? sc[t - off] : 0;
        __syncthreads();
        sc[t] += v;
        __syncthreads();
    }
    if (idx < NE) g_rowptr8[idx] = sc[t] - d;
    if (t == 255) g_bsum[blockIdx.x] = sc[255];
}

// ---- phase B: scan block sums, 8 values/thread serial + one 256-scan ----
__global__ __launch_bounds__(256) void bscan_kernel(int NB, int NE, int E) {
    __shared__ int sc[256];
    int t = threadIdx.x;
    int loc[8];
    int s = 0;
#pragma unroll
    for (int j = 0; j < 8; j++) {
        int i = t * 8 + j;
        int v = (i < NB) ? g_bsum[i] : 0;
        loc[j] = s;
        s += v;
    }
    sc[t] = s;
    __syncthreads();
    for (int off = 1; off < 256; off <<= 1) {
        int v = (t >= off) ? sc[t - off] : 0;
        __syncthreads();
        sc[t] += v;
        __syncthreads();
    }
    int excl = sc[t] - s;
#pragma unroll
    for (int j = 0; j < 8; j++) {
        int i = t * 8 + j;
        if (i < NB) g_boff[i] = excl + loc[j];
    }
    if (t == 0) g_rowptr8[NE] = E;
}

// ---- phase C: add block offsets; finalize rowptr8 + cursor8 ----
__global__ __launch_bounds__(256) void addoff_kernel(int NE) {
    int idx = blockIdx.x * 256 + threadIdx.x;
    if (idx < NE) {
        int base = g_rowptr8[idx] + g_boff[blockIdx.x];
        g_rowptr8[idx] = base;
        g_cursor8[idx] = base;
    }
}

// ---- merged-rowptr scan (N elements) ----
__global__ __launch_bounds__(256) void mlocalscan_kernel(int N) {
    __shared__ int sc[256];
    int t = threadIdx.x;
    int idx = blockIdx.x * 256 + t;
    int d = (idx < N) ? g_mdeg[idx] : 0;
    sc[t] = d;
    __syncthreads();
    for (int off = 1; off < 256; off <<= 1) {
        int v = (t >= off) ? sc[t - off] : 0;
        __syncthreads();
        sc[t] += v;
        __syncthreads();
    }
    if (idx < N) g_mrp[idx] = sc[t] - d;
    if (t == 255) g_bsum2[blockIdx.x] = sc[255];
}

__global__ __launch_bounds__(256) void mbscan_kernel(int NB, int N, int E) {
    __shared__ int sc[256];
    int t = threadIdx.x;
    int v = (t < NB) ? g_bsum2[t] : 0;
    sc[t] = v;
    __syncthreads();
    for (int off = 1; off < 256; off <<= 1) {
        int u = (t >= off) ? sc[t - off] : 0;
        __syncthreads();
        sc[t] += u;
        __syncthreads();
    }
    if (t < NB) g_boff2[t] = sc[t] - v;
    if (t == 0) g_mrp[N] = E;
}

__global__ __launch_bounds__(256) void maddoff_kernel(int N) {
    int idx = blockIdx.x * 256 + threadIdx.x;
    if (idx < N) g_mrp[idx] += g_boff2[blockIdx.x];
}

// ---- scatter edges into group-partitioned CSR buckets (XCD write locality) ----
__global__ void scatter_kernel(int N, int E) {
    int e = blockIdx.x * blockDim.x + threadIdx.x;
    if (e < E) {
        int g = blockIdx.x & (NGRP - 1);
        int pos = atomicAdd(&g_cursor8[g * N + g_dst[e]], 1);
        g_csr[pos] = g_src[e];
    }
}

// ---- merge group-partitioned CSR -> node-major merged CSR (prologue paid ONCE) ----
__global__ __launch_bounds__(256) void merge_kernel(int N) {
    int wid = (blockIdx.x * blockDim.x + threadIdx.x) >> 6;
    if (wid >= N) return;
    int lane = threadIdx.x & 63;
    int mybeg = 0, mycnt = 0;
    if (lane < NGRP) {
        mybeg = g_rowptr8[lane * N + wid];
        mycnt = g_rowptr8[lane * N + wid + 1] - mybeg;
    }
    int incl = mycnt;
#pragma unroll
    for (int off = 1; off < NGRP; off <<= 1) {
        int v = __shfl_up(incl, off, 64);
        if (lane >= off) incl += v;
    }
    int myoff = incl - mycnt;
    int go[NGRP], gb[NGRP];
#pragma unroll
    for (int k = 0; k < NGRP; k++) {
        go[k] = __shfl(myoff, k, 64);
        gb[k] = __shfl(mybeg, k, 64);
    }
    int total = __shfl(incl, NGRP - 1, 64);
    int base = g_mrp[wid];
    for (int i = lane; i < total; i += 64) {
        int g = 0;
#pragma unroll
        for (int k = 1; k < NGRP; k++) g += (i >= go[k]);
        g_mcsr[base + i] = g_csr[gb[g] + i - go[g]];
    }
}

// ---- zb[s][node][16] = z[node][s*16+off] * dinv[node]  (blocked, f32) -> g_agg1 ----
__global__ void zprep_kernel(const void* __restrict__ z, int N) {
    int i = blockIdx.x * blockDim.x + threadIdx.x;
    if (i < N * IN_DIM) {
        int node = i >> 6, c = i & 63;
        int s = c >> 4, off = c & 15;
        g_agg1[(size_t)s * (N * 16) + node * 16 + off] = loadx(z, i, g_in_f32) * g_dinv[node];
    }
}

// ---- layer-1 sliced aggregation: slice pinned via blockIdx&3 -> L2-resident 3.2MB ----
// wave per (node, slice); lane = (eslot 0..3, col 0..15); trivial prologue
__global__ __launch_bounds__(256) void aggzs_kernel(int N) {
    int s = blockIdx.x & (NSLC - 1);
    int w = threadIdx.x >> 6;
    int wid = (blockIdx.x >> 2) * 4 + w;
    if (wid >= N) return;
    int lane = threadIdx.x & 63;
    int col = lane & 15, eslot = lane >> 4;
    const float* tab = g_agg1 + (size_t)s * (N * 16);
    int beg = g_mrp[wid], end = g_mrp[wid + 1];
    float acc = 0.f, acc2 = 0.f;
    int j = beg + eslot;
    for (; j + 4 < end; j += 8) {
        int i0 = g_mcsr[j], i1 = g_mcsr[j + 4];
        acc += tab[i0 * 16 + col];
        acc2 += tab[i1 * 16 + col];
    }
    if (j < end) acc += tab[g_mcsr[j] * 16 + col];
    acc += acc2;
    acc += __shfl_xor(acc, 16, 64);
    acc += __shfl_xor(acc, 32, 64);
    if (lane < 16) {
        float v = (acc + tab[wid * 16 + col]) * g_dinv[wid];
        g_hs1[(size_t)s * (N * 16) + wid * 16 + col] = v;
    }
}

// ---- h = relu(aggz @ W1 + b1): 32 rows/block, 4x4 micro-tile, blocked input ----
__global__ __launch_bounds__(256) void gemm1_kernel(int N) {
    __shared__ float Zs[IN_DIM * 33];  // transposed 64k x 32r, pad 33 -> 8448 B
    int t = threadIdx.x;
    int row0 = blockIdx.x * 32;
#pragma unroll
    for (int s = 0; s < 2; s++) {
        int i = t + s * 256;          // 512 float4s = 32 rows x 16
        int r = i >> 4, k4 = i & 15;
        int row = row0 + r;
        int g = k4 >> 2, off = (k4 & 3) * 4;  // blocked [4][N][16]
        float4 v = make_float4(0.f, 0.f, 0.f, 0.f);
        if (row < N) v = *(const float4*)&g_hs1[(size_t)g * (N * 16) + row * 16 + off];
        Zs[(g * 16 + off + 0) * 33 + r] = v.x;
        Zs[(g * 16 + off + 1) * 33 + r] = v.y;
        Zs[(g * 16 + off + 2) * 33 + r] = v.z;
        Zs[(g * 16 + off + 3) * 33 + r] = v.w;
    }
    __syncthreads();
    int cg = t & 31, rg = t >> 5;  // 32 colgroups x 8 rowgroups
    int c0 = cg * 4, r0 = rg * 4;
    float acc[4][4] = {};
#pragma unroll 8
    for (int k = 0; k < IN_DIM; k++) {
        float b[4];
        *(float4*)b = *(const float4*)&g_W1f[k * HID_DIM + c0];
        float a[4];
        a[0] = Zs[k * 33 + r0];
        a[1] = Zs[k * 33 + r0 + 1];
        a[2] = Zs[k * 33 + r0 + 2];
        a[3] = Zs[k * 33 + r0 + 3];
#pragma unroll
        for (int i = 0; i < 4; i++)
#pragma unroll
            for (int j = 0; j < 4; j++) acc[i][j] = fmaf(a[i], b[j], acc[i][j]);
    }
    float4 bias = *(const float4*)&g_b1f[c0];
#pragma unroll
    for (int i = 0; i < 4; i++) {
        int row = row0 + r0 + i;
        if (row < N) {
            float4 v;
            v.x = fmaxf(acc[i][0] + bias.x, 0.f);
            v.y = fmaxf(acc[i][1] + bias.y, 0.f);
            v.z = fmaxf(acc[i][2] + bias.z, 0.f);
            v.w = fmaxf(acc[i][3] + bias.w, 0.f);
            *(float4*)&g_agg1[(size_t)row * HID_DIM + c0] = v;
        }
    }
}

// ---- hs2 = (h @ W2) * dinv: 32 rows/block, 2x4 micro-tile, blocked output ----
__global__ __launch_bounds__(256) void gemm2_kernel(int N) {
    __shared__ float Zs[64 * 33];  // transposed 64k x 32r, pad 33 -> 8448 B
    int t = threadIdx.x;
    int row0 = blockIdx.x * 32;
    int cg = t & 15, rg = t >> 4;  // 16 colgroups x 16 rowgroups
    int c0 = cg * 4, r0 = rg * 2;
    float acc[2][4] = {};
    for (int kh = 0; kh < 2; kh++) {
        __syncthreads();
#pragma unroll
        for (int s = 0; s < 2; s++) {
            int i = t + s * 256;      // 512 float4s = 32 rows x 16
            int r = i >> 4, k4 = i & 15;
            int row = row0 + r;
            float4 v = make_float4(0.f, 0.f, 0.f, 0.f);
            if (row < N) v = *(const float4*)&g_agg1[(size_t)row * HID_DIM + kh * 64 + k4 * 4];
            Zs[(k4 * 4 + 0) * 33 + r] = v.x;
            Zs[(k4 * 4 + 1) * 33 + r] = v.y;
            Zs[(k4 * 4 + 2) * 33 + r] = v.z;
            Zs[(k4 * 4 + 3) * 33 + r] = v.w;
        }
        __syncthreads();
#pragma unroll 8
        for (int k2 = 0; k2 < 64; k2++) {
            float b[4];
            *(float4*)b = *(const float4*)&g_W2f[(kh * 64 + k2) * OUT_DIM + c0];
            float a[2];
            a[0] = Zs[k2 * 33 + r0];
            a[1] = Zs[k2 * 33 + r0 + 1];
#pragma unroll
            for (int i = 0; i < 2; i++)
#pragma unroll
                for (int j = 0; j < 4; j++) acc[i][j] = fmaf(a[i], b[j], acc[i][j]);
        }
    }
    int g = cg >> 2, off = (cg & 3) * 4;  // blocked output [4][N][16]
#pragma unroll
    for (int i = 0; i < 2; i++) {
        int row = row0 + r0 + i;
        if (row < N) {
            float dn = g_dinv[row];
            float4 v;
            v.x = acc[i][0] * dn;
            v.y = acc[i][1] * dn;
            v.z = acc[i][2] * dn;
            v.w = acc[i][3] * dn;
            *(float4*)&g_hs1[(size_t)g * (N * 16) + row * 16 + off] = v;
        }
    }
}

// ---- layer-2 sliced aggregation; fused bias + dtype store ----
__global__ __launch_bounds__(256) void agg2s_kernel(void* __restrict__ out, int N) {
    int s = blockIdx.x & (NSLC - 1);
    int w = threadIdx.x >> 6;
    int wid = (blockIdx.x >> 2) * 4 + w;
    if (wid >= N) return;
    int lane = threadIdx.x & 63;
    int col = lane & 15, eslot = lane >> 4;
    const float* tab = g_hs1 + (size_t)s * (N * 16);
    int beg = g_mrp[wid], end = g_mrp[wid + 1];
    float acc = 0.f, acc2 = 0.f;
    int j = beg + eslot;
    for (; j + 4 < end; j += 8) {
        int i0 = g_mcsr[j], i1 = g_mcsr[j + 4];
        acc += tab[i0 * 16 + col];
        acc2 += tab[i1 * 16 + col];
    }
    if (j < end) acc += tab[g_mcsr[j] * 16 + col];
    acc += acc2;
    acc += __shfl_xor(acc, 16, 64);
    acc += __shfl_xor(acc, 32, 64);
    if (lane < 16) {
        float v = (acc + tab[wid * 16 + col]) * g_dinv[wid] + g_b2f[s * 16 + col];
        int oc = wid * 64 + s * 16 + col;
        if (g_in_f32) ((float*)out)[oc] = v;
        else ((__hip_bfloat16*)out)[oc] = __float2bfloat16(v);
    }
}

extern "C" void kernel_launch(void* const* d_in, const int* in_sizes, int n_in,
                              void* d_out, int out_size, void* d_ws, size_t ws_size,
                              hipStream_t stream) {
    const void* z  = d_in[0];
    const void* ei = d_in[1];
    const void* W1 = d_in[2];
    const void* b1 = d_in[3];
    const void* W2 = d_in[4];
    const void* b2 = d_in[5];

    const int N = in_sizes[0] / IN_DIM;  // 50000
    const int E = in_sizes[1] / 2;       // 800000
    const int NE = NGRP * N;             // 400000
    const int sliceblocks = NSLC * ((N + 3) / 4);  // 50000

    detect_kernel<<<1, 256, 0, stream>>>((const unsigned short*)z, (const unsigned int*)ei, E);
    prep_kernel<<<NBLK8, 256, 0, stream>>>(W1, b1, W2, b2);
    convert_kernel<<<(E + 255) / 256, 256, 0, stream>>>(ei, N, E);
    dinv_kernel<<<(N + 255) / 256, 256, 0, stream>>>(N);
    localscan_kernel<<<(NE + 255) / 256, 256, 0, stream>>>(NE);
    bscan_kernel<<<1, 256, 0, stream>>>((NE + 255) / 256, NE, E);
    addoff_kernel<<<(NE + 255) / 256, 256, 0, stream>>>(NE);
    mlocalscan_kernel<<<NBLKN, 256, 0, stream>>>(N);
    mbscan_kernel<<<1, 256, 0, stream>>>(NBLKN, N, E);
    maddoff_kernel<<<NBLKN, 256, 0, stream>>>(N);
    scatter_kernel<<<(E + 255) / 256, 256, 0, stream>>>(N, E);
    merge_kernel<<<(N * 64 + 255) / 256, 256, 0, stream>>>(N);

    zprep_kernel<<<(N * IN_DIM + 255) / 256, 256, 0, stream>>>(z, N);
    aggzs_kernel<<<sliceblocks, 256, 0, stream>>>(N);
    gemm1_kernel<<<(N + 31) / 32, 256, 0, stream>>>(N);
    gemm2_kernel<<<(N + 31) / 32, 256, 0, stream>>>(N);
    agg2s_kernel<<<sliceblocks, 256, 0, stream>>>(d_out, N);
}

// Round 8
// 348.978 us; speedup vs baseline: 1.1301x; 1.1301x over previous
//
#include <hip/hip_runtime.h>
#include <hip/hip_bf16.h>

#define N_NODES 50000
#define N_EDGES 800000
#define IN_DIM 64
#define HID_DIM 128
#define OUT_DIM 64
#define NGRP 8
#define NSLC 4                                // feature slices (16 floats = 64B line)
#define NPB 16                                // nodes per agg block
#define ECAP 1024                             // staged edge cap per block
#define NE8 (NGRP * N_NODES)                  // 400000 group-major degree entries
#define NBLK8 ((NE8 + 255) / 256)             // 1563 scan blocks (group-major)
#define NBLKN ((N_NODES + 255) / 256)         // 196 scan blocks (merged)

// ---- device-global scratch (no ws_size dependence) ----
__device__ int g_in_f32;
__device__ int g_is64;
__device__ int g_src[N_EDGES];
__device__ int g_dst[N_EDGES];
__device__ int g_csr[N_EDGES];                // group-major partitioned CSR
__device__ int g_mcsr[N_EDGES];               // merged node-major CSR
__device__ int g_deg8[NE8];                   // [g][v] group-major
__device__ int g_rowptr8[NE8 + 1];
__device__ int g_cursor8[NE8];
__device__ int g_mrp[N_NODES + 1];
__device__ int g_bsum[NBLK8];
__device__ int g_boff[NBLK8];
__device__ int g_bsum2[NBLKN];
__device__ int g_boff2[NBLKN];
__device__ float g_dinv[N_NODES];
__device__ __align__(16) float g_W1f[IN_DIM * HID_DIM];
__device__ __align__(16) float g_W2f[HID_DIM * OUT_DIM];
__device__ __align__(16) float g_b1f[HID_DIM];
__device__ __align__(16) float g_b2f[OUT_DIM];
// g_hs1: aggz out blocked [4][N][16] (N*64), later hs2 blocked [4][N][16]
__device__ __align__(16) float g_hs1[(size_t)N_NODES * HID_DIM];
// g_agg1: zb blocked [4][N][16] (N*64) during aggz, later h row-major (N*128)
__device__ __align__(16) float g_agg1[(size_t)N_NODES * HID_DIM];

__device__ __forceinline__ float loadx(const void* p, int i, int f32) {
    if (f32) return ((const float*)p)[i];
    unsigned int u = ((unsigned int)((const unsigned short*)p)[i]) << 16;
    return __uint_as_float(u);
}

// ---- dtype / index-width detection (data-driven, deterministic) ----
__global__ void detect_kernel(const unsigned short* __restrict__ zw,
                              const unsigned int* __restrict__ ew, int E) {
    __shared__ int s_f32, s_nz;
    if (threadIdx.x == 0) { s_f32 = 0; s_nz = 0; }
    __syncthreads();
    int hit = 0;
    for (int k = 0; k < 64; k++) {
        int i = 2 * ((threadIdx.x * 64 + k) * 97);
        if (((zw[i] >> 7) & 0xFF) == 0xFF) hit = 1;
    }
    if (hit) atomicOr(&s_f32, 1);
    int nz = 0;
    int step = E / 4096;
    for (int k = 0; k < 4; k++) {
        int idx = 1 + 2 * ((threadIdx.x * 4 + k) * step);
        if (ew[idx] != 0) nz = 1;
    }
    if (nz) atomicOr(&s_nz, 1);
    __syncthreads();
    if (threadIdx.x == 0) { g_in_f32 = s_f32; g_is64 = (s_nz == 0) ? 1 : 0; }
}

// ---- zero deg8 + convert weights/biases to f32 scratch (after detect) ----
__global__ void prep_kernel(const void* __restrict__ W1, const void* __restrict__ b1,
                            const void* __restrict__ W2, const void* __restrict__ b2) {
    int i = blockIdx.x * blockDim.x + threadIdx.x;
    if (i < NE8) g_deg8[i] = 0;
    int f32 = g_in_f32;
    if (i < IN_DIM * HID_DIM) g_W1f[i] = loadx(W1, i, f32);
    if (i < HID_DIM * OUT_DIM) g_W2f[i] = loadx(W2, i, f32);
    if (i < HID_DIM) g_b1f[i] = loadx(b1, i, f32);
    if (i < OUT_DIM) g_b2f[i] = loadx(b2, i, f32);
}

// ---- normalize edge_index to int32 + fused per-group degree count ----
__global__ void convert_kernel(const void* __restrict__ ei, int N, int E) {
    int e = blockIdx.x * blockDim.x + threadIdx.x;
    if (e < E) {
        int s, d;
        if (g_is64) {
            const long long* p = (const long long*)ei;
            s = (int)p[e];
            d = (int)p[E + e];
        } else {
            const int* p = (const int*)ei;
            s = p[e];
            d = p[E + e];
        }
        g_src[e] = s;
        g_dst[e] = d;
        int g = blockIdx.x & (NGRP - 1);
        atomicAdd(&g_deg8[g * N + d], 1);
    }
}

// ---- phase A: per-block exclusive scan of deg8 (group-major) ----
__global__ __launch_bounds__(256) void localscan_kernel(int NE) {
    __shared__ int sc[256];
    int t = threadIdx.x;
    int idx = blockIdx.x * 256 + t;
    int d = (idx < NE) ? g_deg8[idx] : 0;
    sc[t] = d;
    __syncthreads();
    for (int off = 1; off < 256; off <<= 1) {
        int v = (t >= off) ? sc[t - off] : 0;
        __syncthreads();
        sc[t] += v;
        __syncthreads();
    }
    if (idx < NE) g_rowptr8[idx] = sc[t] - d;
    if (t == 255) g_bsum[blockIdx.x] = sc[255];
}

// ---- phase B: scan block sums, 8 values/thread serial + one 256-scan ----
__global__ __launch_bounds__(256) void bscan_kernel(int NB, int NE, int E) {
    __shared__ int sc[256];
    int t = threadIdx.x;
    int loc[8];
    int s = 0;
#pragma unroll
    for (int j = 0; j < 8; j++) {
        int i = t * 8 + j;
        int v = (i < NB) ? g_bsum[i] : 0;
        loc[j] = s;
        s += v;
    }
    sc[t] = s;
    __syncthreads();
    for (int off = 1; off < 256; off <<= 1) {
        int v = (t >= off) ? sc[t - off] : 0;
        __syncthreads();
        sc[t] += v;
        __syncthreads();
    }
    int excl = sc[t] - s;
#pragma unroll
    for (int j = 0; j < 8; j++) {
        int i = t * 8 + j;
        if (i < NB) g_boff[i] = excl + loc[j];
    }
    if (t == 0) g_rowptr8[NE] = E;
}

// ---- phase C: add block offsets; finalize rowptr8 + cursor8 ----
__global__ __launch_bounds__(256) void addoff_kernel(int NE) {
    int idx = blockIdx.x * 256 + threadIdx.x;
    if (idx < NE) {
        int base = g_rowptr8[idx] + g_boff[blockIdx.x];
        g_rowptr8[idx] = base;
        g_cursor8[idx] = base;
    }
}

// ---- merged-rowptr local scan (N elements), fused dinv ----
__global__ __launch_bounds__(256) void mlocalscan_kernel(int N) {
    __shared__ int sc[256];
    int t = threadIdx.x;
    int idx = blockIdx.x * 256 + t;
    int d = 0;
    if (idx < N) {
#pragma unroll
        for (int g = 0; g < NGRP; g++) d += g_deg8[g * N + idx];
        g_dinv[idx] = rsqrtf((float)d + 1.0f);  // +1 = self loop
    }
    sc[t] = d;
    __syncthreads();
    for (int off = 1; off < 256; off <<= 1) {
        int v = (t >= off) ? sc[t - off] : 0;
        __syncthreads();
        sc[t] += v;
        __syncthreads();
    }
    if (idx < N) g_mrp[idx] = sc[t] - d;
    if (t == 255) g_bsum2[blockIdx.x] = sc[255];
}

__global__ __launch_bounds__(256) void mbscan_kernel(int NB, int N, int E) {
    __shared__ int sc[256];
    int t = threadIdx.x;
    int v = (t < NB) ? g_bsum2[t] : 0;
    sc[t] = v;
    __syncthreads();
    for (int off = 1; off < 256; off <<= 1) {
        int u = (t >= off) ? sc[t - off] : 0;
        __syncthreads();
        sc[t] += u;
        __syncthreads();
    }
    if (t < NB) g_boff2[t] = sc[t] - v;
    if (t == 0) g_mrp[N] = E;
}

__global__ __launch_bounds__(256) void maddoff_kernel(int N) {
    int idx = blockIdx.x * 256 + threadIdx.x;
    if (idx < N) g_mrp[idx] += g_boff2[blockIdx.x];
}

// ---- scatter edges into group-partitioned CSR buckets (XCD write locality) ----
__global__ void scatter_kernel(int N, int E) {
    int e = blockIdx.x * blockDim.x + threadIdx.x;
    if (e < E) {
        int g = blockIdx.x & (NGRP - 1);
        int pos = atomicAdd(&g_cursor8[g * N + g_dst[e]], 1);
        g_csr[pos] = g_src[e];
    }
}

// ---- merge group-partitioned CSR -> node-major merged CSR (prologue paid ONCE) ----
__global__ __launch_bounds__(256) void merge_kernel(int N) {
    int wid = (blockIdx.x * blockDim.x + threadIdx.x) >> 6;
    if (wid >= N) return;
    int lane = threadIdx.x & 63;
    int mybeg = 0, mycnt = 0;
    if (lane < NGRP) {
        mybeg = g_rowptr8[lane * N + wid];
        mycnt = g_rowptr8[lane * N + wid + 1] - mybeg;
    }
    int incl = mycnt;
#pragma unroll
    for (int off = 1; off < NGRP; off <<= 1) {
        int v = __shfl_up(incl, off, 64);
        if (lane >= off) incl += v;
    }
    int myoff = incl - mycnt;
    int go[NGRP], gb[NGRP];
#pragma unroll
    for (int k = 0; k < NGRP; k++) {
        go[k] = __shfl(myoff, k, 64);
        gb[k] = __shfl(mybeg, k, 64);
    }
    int total = __shfl(incl, NGRP - 1, 64);
    int base = g_mrp[wid];
    for (int i = lane; i < total; i += 64) {
        int g = 0;
#pragma unroll
        for (int k = 1; k < NGRP; k++) g += (i >= go[k]);
        g_mcsr[base + i] = g_csr[gb[g] + i - go[g]];
    }
}

// ---- zb[s][node][16] = z[node][s*16+off] * dinv[node]  (blocked, f32) -> g_agg1 ----
__global__ void zprep_kernel(const void* __restrict__ z, int N) {
    int i = blockIdx.x * blockDim.x + threadIdx.x;
    if (i < N * IN_DIM) {
        int node = i >> 6, c = i & 63;
        int s = c >> 4, off = c & 15;
        g_agg1[(size_t)s * (N * 16) + node * 16 + off] = loadx(z, i, g_in_f32) * g_dinv[node];
    }
}

// ---- block-staged sliced aggregation: 16 nodes x 1 slice per block ----
// staging: mrp[17] + contiguous edge range into LDS (2 latency rounds / 16 nodes),
// then each wave gathers 4 nodes with LDS-sourced indices (no global index chain).
// slice pinned via blockIdx&3 -> round-robin XCD -> 3.2MB table L2-resident.
template <int LAYER2>
__global__ __launch_bounds__(256) void aggslc_kernel(void* __restrict__ outp, int N) {
    __shared__ int rp[NPB + 1];
    __shared__ int eidx[ECAP];
    int s = blockIdx.x & (NSLC - 1);
    int n0 = (blockIdx.x >> 2) * NPB;
    int t = threadIdx.x;
    if (t <= NPB) {
        int idx = n0 + t;
        rp[t] = g_mrp[idx <= N ? idx : N];
    }
    __syncthreads();
    int base = rp[0];
    int range = rp[NPB] - base;
    bool staged = (range <= ECAP);
    if (staged) {
        for (int i = t; i < range; i += 256) eidx[i] = g_mcsr[base + i];
    }
    __syncthreads();
    const float* tab = (LAYER2 ? g_hs1 : g_agg1) + (size_t)s * ((size_t)N * 16);
    int lane = t & 63;
    int w4 = (t >> 6) * 4;
    int col = lane & 15, eslot = lane >> 4;
    float res[4];
#pragma unroll
    for (int k = 0; k < 4; k++) {
        int jb = rp[w4 + k] - base + eslot;
        int je = rp[w4 + k + 1] - base;
        float a0 = 0.f, a1 = 0.f, a2 = 0.f, a3 = 0.f;
        int j = jb;
        if (staged) {
            for (; j + 12 < je; j += 16) {
                int i0 = eidx[j], i1 = eidx[j + 4], i2 = eidx[j + 8], i3 = eidx[j + 12];
                a0 += tab[i0 * 16 + col];
                a1 += tab[i1 * 16 + col];
                a2 += tab[i2 * 16 + col];
                a3 += tab[i3 * 16 + col];
            }
            for (; j < je; j += 4) a0 += tab[eidx[j] * 16 + col];
        } else {  // essentially-never fallback: direct global index walk
            for (; j < je; j += 4) a0 += tab[g_mcsr[base + j] * 16 + col];
        }
        float a = (a0 + a1) + (a2 + a3);
        a += __shfl_xor(a, 16, 64);
        a += __shfl_xor(a, 32, 64);
        res[k] = a;
    }
    if (lane < 16) {
#pragma unroll
        for (int k = 0; k < 4; k++) {
            int nk = n0 + w4 + k;
            if (nk < N) {
                float v = (res[k] + tab[(size_t)nk * 16 + col]) * g_dinv[nk];
                if (LAYER2) {
                    v += g_b2f[s * 16 + col];
                    int oc = nk * 64 + s * 16 + col;
                    if (g_in_f32) ((float*)outp)[oc] = v;
                    else ((__hip_bfloat16*)outp)[oc] = __float2bfloat16(v);
                } else {
                    g_hs1[(size_t)s * ((size_t)N * 16) + nk * 16 + col] = v;
                }
            }
        }
    }
}

// ---- h = relu(aggz @ W1 + b1): 32 rows/block, 4x4 micro-tile, blocked input ----
__global__ __launch_bounds__(256) void gemm1_kernel(int N) {
    __shared__ float Zs[IN_DIM * 33];  // transposed 64k x 32r, pad 33 -> 8448 B
    int t = threadIdx.x;
    int row0 = blockIdx.x * 32;
#pragma unroll
    for (int s = 0; s < 2; s++) {
        int i = t + s * 256;          // 512 float4s = 32 rows x 16
        int r = i >> 4, k4 = i & 15;
        int row = row0 + r;
        int g = k4 >> 2, off = (k4 & 3) * 4;  // blocked [4][N][16]
        float4 v = make_float4(0.f, 0.f, 0.f, 0.f);
        if (row < N) v = *(const float4*)&g_hs1[(size_t)g * (N * 16) + row * 16 + off];
        Zs[(g * 16 + off + 0) * 33 + r] = v.x;
        Zs[(g * 16 + off + 1) * 33 + r] = v.y;
        Zs[(g * 16 + off + 2) * 33 + r] = v.z;
        Zs[(g * 16 + off + 3) * 33 + r] = v.w;
    }
    __syncthreads();
    int cg = t & 31, rg = t >> 5;  // 32 colgroups x 8 rowgroups
    int c0 = cg * 4, r0 = rg * 4;
    float acc[4][4] = {};
#pragma unroll 8
    for (int k = 0; k < IN_DIM; k++) {
        float b[4];
        *(float4*)b = *(const float4*)&g_W1f[k * HID_DIM + c0];
        float a[4];
        a[0] = Zs[k * 33 + r0];
        a[1] = Zs[k * 33 + r0 + 1];
        a[2] = Zs[k * 33 + r0 + 2];
        a[3] = Zs[k * 33 + r0 + 3];
#pragma unroll
        for (int i = 0; i < 4; i++)
#pragma unroll
            for (int j = 0; j < 4; j++) acc[i][j] = fmaf(a[i], b[j], acc[i][j]);
    }
    float4 bias = *(const float4*)&g_b1f[c0];
#pragma unroll
    for (int i = 0; i < 4; i++) {
        int row = row0 + r0 + i;
        if (row < N) {
            float4 v;
            v.x = fmaxf(acc[i][0] + bias.x, 0.f);
            v.y = fmaxf(acc[i][1] + bias.y, 0.f);
            v.z = fmaxf(acc[i][2] + bias.z, 0.f);
            v.w = fmaxf(acc[i][3] + bias.w, 0.f);
            *(float4*)&g_agg1[(size_t)row * HID_DIM + c0] = v;
        }
    }
}

// ---- hs2 = (h @ W2) * dinv: 32 rows/block, 2x4 micro-tile, blocked output ----
__global__ __launch_bounds__(256) void gemm2_kernel(int N) {
    __shared__ float Zs[64 * 33];  // transposed 64k x 32r, pad 33 -> 8448 B
    int t = threadIdx.x;
    int row0 = blockIdx.x * 32;
    int cg = t & 15, rg = t >> 4;  // 16 colgroups x 16 rowgroups
    int c0 = cg * 4, r0 = rg * 2;
    float acc[2][4] = {};
    for (int kh = 0; kh < 2; kh++) {
        __syncthreads();
#pragma unroll
        for (int s = 0; s < 2; s++) {
            int i = t + s * 256;      // 512 float4s = 32 rows x 16
            int r = i >> 4, k4 = i & 15;
            int row = row0 + r;
            float4 v = make_float4(0.f, 0.f, 0.f, 0.f);
            if (row < N) v = *(const float4*)&g_agg1[(size_t)row * HID_DIM + kh * 64 + k4 * 4];
            Zs[(k4 * 4 + 0) * 33 + r] = v.x;
            Zs[(k4 * 4 + 1) * 33 + r] = v.y;
            Zs[(k4 * 4 + 2) * 33 + r] = v.z;
            Zs[(k4 * 4 + 3) * 33 + r] = v.w;
        }
        __syncthreads();
#pragma unroll 8
        for (int k2 = 0; k2 < 64; k2++) {
            float b[4];
            *(float4*)b = *(const float4*)&g_W2f[(kh * 64 + k2) * OUT_DIM + c0];
            float a[2];
            a[0] = Zs[k2 * 33 + r0];
            a[1] = Zs[k2 * 33 + r0 + 1];
#pragma unroll
            for (int i = 0; i < 2; i++)
#pragma unroll
                for (int j = 0; j < 4; j++) acc[i][j] = fmaf(a[i], b[j], acc[i][j]);
        }
    }
    int g = cg >> 2, off = (cg & 3) * 4;  // blocked output [4][N][16]
#pragma unroll
    for (int i = 0; i < 2; i++) {
        int row = row0 + r0 + i;
        if (row < N) {
            float dn = g_dinv[row];
            float4 v;
            v.x = acc[i][0] * dn;
            v.y = acc[i][1] * dn;
            v.z = acc[i][2] * dn;
            v.w = acc[i][3] * dn;
            *(float4*)&g_hs1[(size_t)g * (N * 16) + row * 16 + off] = v;
        }
    }
}

extern "C" void kernel_launch(void* const* d_in, const int* in_sizes, int n_in,
                              void* d_out, int out_size, void* d_ws, size_t ws_size,
                              hipStream_t stream) {
    const void* z  = d_in[0];
    const void* ei = d_in[1];
    const void* W1 = d_in[2];
    const void* b1 = d_in[3];
    const void* W2 = d_in[4];
    const void* b2 = d_in[5];

    const int N = in_sizes[0] / IN_DIM;  // 50000
    const int E = in_sizes[1] / 2;       // 800000
    const int NE = NGRP * N;             // 400000
    const int aggblocks = NSLC * ((N + NPB - 1) / NPB);  // 12500

    detect_kernel<<<1, 256, 0, stream>>>((const unsigned short*)z, (const unsigned int*)ei, E);
    prep_kernel<<<NBLK8, 256, 0, stream>>>(W1, b1, W2, b2);
    convert_kernel<<<(E + 255) / 256, 256, 0, stream>>>(ei, N, E);
    localscan_kernel<<<(NE + 255) / 256, 256, 0, stream>>>(NE);
    bscan_kernel<<<1, 256, 0, stream>>>((NE + 255) / 256, NE, E);
    addoff_kernel<<<(NE + 255) / 256, 256, 0, stream>>>(NE);
    mlocalscan_kernel<<<NBLKN, 256, 0, stream>>>(N);
    mbscan_kernel<<<1, 256, 0, stream>>>(NBLKN, N, E);
    maddoff_kernel<<<NBLKN, 256, 0, stream>>>(N);
    scatter_kernel<<<(E + 255) / 256, 256, 0, stream>>>(N, E);
    merge_kernel<<<(N * 64 + 255) / 256, 256, 0, stream>>>(N);

    zprep_kernel<<<(N * IN_DIM + 255) / 256, 256, 0, stream>>>(z, N);
    aggslc_kernel<0><<<aggblocks, 256, 0, stream>>>(d_out, N);
    gemm1_kernel<<<(N + 31) / 32, 256, 0, stream>>>(N);
    gemm2_kernel<<<(N + 31) / 32, 256, 0, stream>>>(N);
    aggslc_kernel<1><<<aggblocks, 256, 0, stream>>>(d_out, N);
}